// Round 7
// baseline (615.981 us; speedup 1.0000x reference)
//
#include <hip/hip_runtime.h>
#include <cstdint>
#include <cstddef>

#define SEQ_ 4096
#define DIM_ 1280
#define NHEAD_ 20
#define HDIM_ 64
#define FFN_ 5120
#define SEG_ 512
#define QKVN_ 3840

typedef __attribute__((ext_vector_type(8))) short bf16x8;
typedef __attribute__((ext_vector_type(4))) float f32x4;
typedef __attribute__((ext_vector_type(8))) unsigned short us8;
typedef __attribute__((ext_vector_type(4))) unsigned short us4;

__device__ __forceinline__ unsigned short f2b(float f) {
  unsigned int u = __builtin_bit_cast(unsigned int, f);
  u += 0x7fffu + ((u >> 16) & 1u);
  return (unsigned short)(u >> 16);
}

__device__ __forceinline__ void gload_lds16(const void* g, void* l) {
  __builtin_amdgcn_global_load_lds(
      (const __attribute__((address_space(1))) unsigned int*)g,
      (__attribute__((address_space(3))) unsigned int*)l, 16, 0, 0);
}

// ---------- transpose + f32->bf16: out[C][R] = bf16(in[R][C]) ----------
__global__ __launch_bounds__(256) void transp_bf16_kernel(
    const float* __restrict__ in, unsigned short* __restrict__ out, int R, int C) {
  __shared__ float tile[32][33];
  int c0 = blockIdx.x * 32, r0 = blockIdx.y * 32;
  int tx = threadIdx.x & 31, ty = threadIdx.x >> 5;
#pragma unroll
  for (int i = 0; i < 32; i += 8)
    tile[ty + i][tx] = in[(size_t)(r0 + ty + i) * C + c0 + tx];
  __syncthreads();
#pragma unroll
  for (int i = 0; i < 32; i += 8)
    out[(size_t)(c0 + ty + i) * R + r0 + tx] = f2b(tile[tx][ty + i]);
}

// ---------- layernorm f32 -> bf16 ----------
__global__ __launch_bounds__(256) void ln_kernel(
    const float* __restrict__ in, const float* __restrict__ g,
    const float* __restrict__ b, unsigned short* __restrict__ out) {
  int row = blockIdx.x, tid = threadIdx.x;
  int l = tid & 63, w = tid >> 6;
  const float* x = in + (size_t)row * DIM_;
  float v[5], s = 0.f, s2 = 0.f;
#pragma unroll
  for (int i = 0; i < 5; ++i) {
    v[i] = x[tid + i * 256];
    s += v[i];
    s2 += v[i] * v[i];
  }
#pragma unroll
  for (int off = 1; off < 64; off <<= 1) {
    s += __shfl_xor(s, off);
    s2 += __shfl_xor(s2, off);
  }
  __shared__ float red[8];
  if (l == 0) { red[w * 2] = s; red[w * 2 + 1] = s2; }
  __syncthreads();
  s = red[0] + red[2] + red[4] + red[6];
  s2 = red[1] + red[3] + red[5] + red[7];
  float mu = s * (1.f / DIM_);
  float var = s2 * (1.f / DIM_) - mu * mu;
  float rs = rsqrtf(var + 1e-5f);
#pragma unroll
  for (int i = 0; i < 5; ++i) {
    int c = tid + i * 256;
    out[(size_t)row * DIM_ + c] = f2b((v[i] - mu) * rs * g[c] + b[c]);
  }
}

// ---------- 128x128 GEMM, BK=32, 4 waves, 2-phase dbuf, 32KB LDS ----------
// Occupancy-first: VGPR<=~96, LDS 32KB -> 4-5 blocks/CU co-resident; grids
// >=640 via split-K so the m114 inter-block overlap absorbs barrier drains.
enum { EPI_QKV = 0, EPI_GELU = 3, EPI_PART = 4 };

template <int EPI>
__global__ __launch_bounds__(256, 4) void gemm_kernel(
    const unsigned short* __restrict__ A, int lda,
    const unsigned short* __restrict__ Bt, int ldb,
    const float* __restrict__ bias, const float* __restrict__ bias2,
    void* __restrict__ out0, void* __restrict__ out1, void* __restrict__ out2,
    int M, int N, int Ksub) {
  __shared__ unsigned short Asm_[2][512 * 8];  // [buf][kg:4][row:128][8]
  __shared__ unsigned short Bsm_[2][512 * 8];
  int tid = threadIdx.x;
  int l = tid & 63, w = tid >> 6;
  // XCD-chunked block swizzle per z-plane (all x*y grids %8==0)
  int nwg = gridDim.x * gridDim.y;
  int orig = blockIdx.y * gridDim.x + blockIdx.x;
  int swz = (orig & 7) * (nwg >> 3) + (orig >> 3);
  int bx = swz % gridDim.x, by = swz / gridDim.x;
  int m0 = by * 128, n0 = bx * 128;
  int wm = (w >> 1) * 64, wn = (w & 1) * 64;
  int r16 = l & 15, kg = l >> 4;
  // split-K offset
  A += (size_t)blockIdx.z * Ksub;
  Bt += (size_t)blockIdx.z * Ksub;
  // per-thread staging source addresses (chunk c = i*256 + w*64 + l)
  int c0_ = w * 64 + l, c1_ = 256 + w * 64 + l;
  const unsigned short* aA0 = A + (size_t)(m0 + (c0_ & 127)) * lda + (c0_ >> 7) * 8;
  const unsigned short* aA1 = A + (size_t)(m0 + (c1_ & 127)) * lda + (c1_ >> 7) * 8;
  const unsigned short* aB0 = Bt + (size_t)(n0 + (c0_ & 127)) * ldb + (c0_ >> 7) * 8;
  const unsigned short* aB1 = Bt + (size_t)(n0 + (c1_ & 127)) * ldb + (c1_ >> 7) * 8;
  f32x4 acc[4][4] = {};
  int nk = Ksub >> 5;  // 20/40/80: even

#define STAGE(b, kt_)                                                \
  do {                                                               \
    int kb = (kt_) * 32;                                             \
    gload_lds16(aA0 + kb, (char*)Asm_[b] + (w * 64) * 16);           \
    gload_lds16(aA1 + kb, (char*)Asm_[b] + (256 + w * 64) * 16);     \
    gload_lds16(aB0 + kb, (char*)Bsm_[b] + (w * 64) * 16);           \
    gload_lds16(aB1 + kb, (char*)Bsm_[b] + (256 + w * 64) * 16);     \
  } while (0)

#define COMPUTE(b)                                                                        \
  do {                                                                                    \
    bf16x8 af[4], bfr[4];                                                                 \
    _Pragma("unroll") for (int mi = 0; mi < 4; ++mi) af[mi] =                             \
        *(const bf16x8*)((const char*)Asm_[b] + ((kg << 7) + wm + mi * 16 + r16) * 16);   \
    _Pragma("unroll") for (int ni = 0; ni < 4; ++ni) bfr[ni] =                            \
        *(const bf16x8*)((const char*)Bsm_[b] + ((kg << 7) + wn + ni * 16 + r16) * 16);   \
    _Pragma("unroll") for (int mi = 0; mi < 4; ++mi)                                      \
        _Pragma("unroll") for (int ni = 0; ni < 4; ++ni) acc[mi][ni] =                    \
            __builtin_amdgcn_mfma_f32_16x16x32_bf16(af[mi], bfr[ni], acc[mi][ni], 0, 0, 0); \
  } while (0)

  STAGE(0, 0);
  __syncthreads();
  for (int kt = 0; kt < nk; kt += 2) {
    STAGE(1, kt + 1);
    COMPUTE(0);
    __syncthreads();
    if (kt + 2 < nk) STAGE(0, kt + 2);
    COMPUTE(1);
    __syncthreads();
  }
#undef STAGE
#undef COMPUTE

  int rg = (l >> 4) * 4;
#pragma unroll
  for (int mi = 0; mi < 4; ++mi) {
#pragma unroll
    for (int ni = 0; ni < 4; ++ni) {
      int row = m0 + wm + mi * 16 + rg;
      int col = n0 + wn + ni * 16 + r16;
      f32x4 v = acc[mi][ni];
      if constexpr (EPI == EPI_QKV) {
        if (col < DIM_) {  // Q (+bq)
          unsigned short* O = (unsigned short*)out0;
          float bb = bias[col];
#pragma unroll
          for (int j = 0; j < 4; ++j) O[(size_t)(row + j) * DIM_ + col] = f2b(v[j] + bb);
        } else if (col < 2 * DIM_) {  // K (no bias)
          unsigned short* O = (unsigned short*)out1;
          int cc = col - DIM_;
#pragma unroll
          for (int j = 0; j < 4; ++j) O[(size_t)(row + j) * DIM_ + cc] = f2b(v[j]);
        } else {  // V (+bv), transposed store -> Vt[d][s]
          unsigned short* O = (unsigned short*)out2;
          int cc = col - 2 * DIM_;
          float bb = bias2[cc];
          us4 pk;
#pragma unroll
          for (int j = 0; j < 4; ++j) pk[j] = f2b(v[j] + bb);
          *(us4*)(O + (size_t)cc * SEQ_ + row) = pk;
        }
      } else if constexpr (EPI == EPI_GELU) {
        unsigned short* O = (unsigned short*)out0;
        float bb = bias[col];
#pragma unroll
        for (int j = 0; j < 4; ++j) {
          float t = v[j] + bb;
          t = 0.5f * t * (1.f + erff(t * 0.70710678118f));
          O[(size_t)(row + j) * N + col] = f2b(t);
        }
      } else {  // EPI_PART: raw f32 partial per K-split
        float* O = (float*)out0 + (size_t)blockIdx.z * M * N;
#pragma unroll
        for (int j = 0; j < 4; ++j) O[(size_t)(row + j) * N + col] = v[j];
      }
    }
  }
}

// ---------- split-K reduce: out = p0 + p1 + bias + res (f32) ----------
__global__ __launch_bounds__(256) void reduce_kernel(
    const float* __restrict__ part, const float* __restrict__ bias,
    const float* __restrict__ res, float* __restrict__ out) {
  const size_t MN = (size_t)SEQ_ * DIM_;
  for (size_t i = blockIdx.x * 256 + threadIdx.x; i * 4 < MN; i += (size_t)gridDim.x * 256) {
    size_t e = i * 4;
    f32x4 a = *(const f32x4*)(part + e);
    f32x4 b = *(const f32x4*)(part + MN + e);
    f32x4 r = *(const f32x4*)(res + e);
    f32x4 bb = *(const f32x4*)(bias + (int)(e % DIM_));
    f32x4 o = a + b + r + bb;
    *(f32x4*)(out + e) = o;
  }
}

// ---------- attention: per (head, seg, 64-row q chunk) ----------
__global__ __launch_bounds__(256) void attn_kernel(
    const unsigned short* __restrict__ Q, const unsigned short* __restrict__ Kb,
    const unsigned short* __restrict__ Vt, unsigned short* __restrict__ O) {
  __shared__ float S[64][512];
  int tid = threadIdx.x;
  int l = tid & 63, w = tid >> 6;
  int orig = blockIdx.x;
  int b = (orig & 7) * (gridDim.x >> 3) + (orig >> 3);
  int qc = b & 7, seg = (b >> 3) & 7, hh = b >> 6;
  int r16 = l & 15, kg = l >> 4, rg = (l >> 4) * 4;
  int qrow0 = seg * SEG_ + qc * 64 + w * 16;
  bf16x8 aq[2];
#pragma unroll
  for (int ks = 0; ks < 2; ++ks)
    aq[ks] = *(const bf16x8*)(Q + (size_t)(qrow0 + r16) * DIM_ + hh * HDIM_ + ks * 32 + kg * 8);
#pragma unroll 4
  for (int kc = 0; kc < 32; ++kc) {
    f32x4 acc = {};
#pragma unroll
    for (int ks = 0; ks < 2; ++ks) {
      bf16x8 bk = *(const bf16x8*)(Kb + (size_t)(seg * SEG_ + kc * 16 + r16) * DIM_ +
                                   hh * HDIM_ + ks * 32 + kg * 8);
      acc = __builtin_amdgcn_mfma_f32_16x16x32_bf16(aq[ks], bk, acc, 0, 0, 0);
    }
#pragma unroll
    for (int j = 0; j < 4; ++j)
      S[w * 16 + rg + j][kc * 16 + r16] = acc[j] * 0.125f;
  }
#pragma unroll 2
  for (int r = 0; r < 16; ++r) {
    float* Sr = &S[w * 16 + r][0];
    f32x4 v0 = *(const f32x4*)(Sr + l * 8);
    f32x4 v1 = *(const f32x4*)(Sr + l * 8 + 4);
    float m = fmaxf(fmaxf(fmaxf(v0[0], v0[1]), fmaxf(v0[2], v0[3])),
                    fmaxf(fmaxf(v1[0], v1[1]), fmaxf(v1[2], v1[3])));
#pragma unroll
    for (int off = 1; off < 64; off <<= 1) m = fmaxf(m, __shfl_xor(m, off));
    float ev[8];
    ev[0] = v0[0]; ev[1] = v0[1]; ev[2] = v0[2]; ev[3] = v0[3];
    ev[4] = v1[0]; ev[5] = v1[1]; ev[6] = v1[2]; ev[7] = v1[3];
    float sum = 0.f;
#pragma unroll
    for (int j = 0; j < 8; ++j) { ev[j] = __expf(ev[j] - m); sum += ev[j]; }
#pragma unroll
    for (int off = 1; off < 64; off <<= 1) sum += __shfl_xor(sum, off);
    float inv = 1.f / sum;
    us8 pk;
#pragma unroll
    for (int j = 0; j < 8; ++j) pk[j] = f2b(ev[j] * inv);
    *(us8*)((unsigned short*)Sr + ((l ^ (r & 7)) * 8)) = pk;
  }
  f32x4 oacc[4] = {};
  const unsigned short* Pr = (const unsigned short*)&S[w * 16 + r16][0];
  int rowx = r16 & 7;
#pragma unroll 2
  for (int ks = 0; ks < 16; ++ks) {
    int chunk = (ks * 4 + kg) ^ rowx;
    bf16x8 pa = *(const bf16x8*)(Pr + chunk * 8);
#pragma unroll
    for (int df = 0; df < 4; ++df) {
      bf16x8 bv = *(const bf16x8*)(Vt + (size_t)(hh * HDIM_ + df * 16 + r16) * SEQ_ +
                                   seg * SEG_ + ks * 32 + kg * 8);
      oacc[df] = __builtin_amdgcn_mfma_f32_16x16x32_bf16(pa, bv, oacc[df], 0, 0, 0);
    }
  }
#pragma unroll
  for (int df = 0; df < 4; ++df)
#pragma unroll
    for (int j = 0; j < 4; ++j)
      O[(size_t)(qrow0 + rg + j) * DIM_ + hh * HDIM_ + df * 16 + r16] = f2b(oacc[df][j]);
}

extern "C" void kernel_launch(void* const* d_in, const int* in_sizes, int n_in,
                              void* d_out, int out_size, void* d_ws, size_t ws_size,
                              hipStream_t stream) {
  (void)in_sizes; (void)n_in; (void)out_size; (void)ws_size;
  const float* hidden = (const float*)d_in[0];
  const float* Wq = (const float*)d_in[2];
  const float* bq = (const float*)d_in[3];
  const float* Wk = (const float*)d_in[4];
  const float* Wv = (const float*)d_in[5];
  const float* bv = (const float*)d_in[6];
  const float* Wo = (const float*)d_in[7];
  const float* bo = (const float*)d_in[8];
  const float* g1 = (const float*)d_in[9];
  const float* b1 = (const float*)d_in[10];
  const float* Wf1 = (const float*)d_in[11];
  const float* bf1 = (const float*)d_in[12];
  const float* Wf2 = (const float*)d_in[13];
  const float* bf2 = (const float*)d_in[14];
  const float* g2 = (const float*)d_in[15];
  const float* b2 = (const float*)d_in[16];

  char* p = (char*)d_ws;
  auto alloc = [&](size_t bytes) {
    char* r = p;
    p += (bytes + 255) & ~(size_t)255;
    return r;
  };
  unsigned short* xln   = (unsigned short*)alloc((size_t)SEQ_ * DIM_ * 2);
  unsigned short* Wqkvt = (unsigned short*)alloc((size_t)DIM_ * QKVN_ * 2);
  unsigned short* Wot   = (unsigned short*)alloc((size_t)DIM_ * DIM_ * 2);
  unsigned short* Wf1t  = (unsigned short*)alloc((size_t)DIM_ * FFN_ * 2);
  unsigned short* Wf2t  = (unsigned short*)alloc((size_t)DIM_ * FFN_ * 2);
  unsigned short* Qb    = (unsigned short*)alloc((size_t)SEQ_ * DIM_ * 2);
  unsigned short* Kbf   = (unsigned short*)alloc((size_t)SEQ_ * DIM_ * 2);
  unsigned short* Vtb   = (unsigned short*)alloc((size_t)SEQ_ * DIM_ * 2);
  unsigned short* attnb = (unsigned short*)alloc((size_t)SEQ_ * DIM_ * 2);
  float*          hbuf  = (float*)alloc((size_t)SEQ_ * DIM_ * 4);
  unsigned short* ybuf  = (unsigned short*)alloc((size_t)SEQ_ * DIM_ * 2);
  unsigned short* gbuf  = (unsigned short*)alloc((size_t)SEQ_ * FFN_ * 2);
  // Wo partials (2 x SEQ*DIM f32 = 41.9MB) alias gbuf (41.9MB, not yet live);
  // FFN2 partials alias Qb..attnb (4 x SEQ*DIM bf16 = 41.9MB, dead after Wo).
  float* partW = (float*)gbuf;
  float* partF = (float*)Qb;

  transp_bf16_kernel<<<dim3(DIM_ / 32, DIM_ / 32), 256, 0, stream>>>(Wq, Wqkvt, DIM_, DIM_);
  transp_bf16_kernel<<<dim3(DIM_ / 32, DIM_ / 32), 256, 0, stream>>>(Wk, Wqkvt + (size_t)DIM_ * DIM_, DIM_, DIM_);
  transp_bf16_kernel<<<dim3(DIM_ / 32, DIM_ / 32), 256, 0, stream>>>(Wv, Wqkvt + (size_t)2 * DIM_ * DIM_, DIM_, DIM_);
  transp_bf16_kernel<<<dim3(DIM_ / 32, DIM_ / 32), 256, 0, stream>>>(Wo, Wot, DIM_, DIM_);
  transp_bf16_kernel<<<dim3(FFN_ / 32, DIM_ / 32), 256, 0, stream>>>(Wf1, Wf1t, DIM_, FFN_);
  transp_bf16_kernel<<<dim3(DIM_ / 32, FFN_ / 32), 256, 0, stream>>>(Wf2, Wf2t, FFN_, DIM_);
  ln_kernel<<<SEQ_, 256, 0, stream>>>(hidden, g1, b1, xln);
  // fused QKV projection: 960 blocks
  gemm_kernel<EPI_QKV><<<dim3(QKVN_ / 128, SEQ_ / 128), 256, 0, stream>>>(
      xln, DIM_, Wqkvt, DIM_, bq, bv, Qb, Kbf, Vtb, SEQ_, QKVN_, DIM_);
  attn_kernel<<<NHEAD_ * 8 * 8, 256, 0, stream>>>(Qb, Kbf, Vtb, attnb);
  // Wo split-K=2 -> partials (640 blocks), reduce adds bias+residual -> hbuf
  gemm_kernel<EPI_PART><<<dim3(DIM_ / 128, SEQ_ / 128, 2), 256, 0, stream>>>(
      attnb, DIM_, Wot, DIM_, nullptr, nullptr, partW, nullptr, nullptr, SEQ_, DIM_, DIM_ / 2);
  reduce_kernel<<<2048, 256, 0, stream>>>(partW, bo, hidden, hbuf);
  ln_kernel<<<SEQ_, 256, 0, stream>>>(hbuf, g2, b2, ybuf);
  // FFN1 + GELU: 1280 blocks (overwrites partW region after reduce consumed it)
  gemm_kernel<EPI_GELU><<<dim3(FFN_ / 128, SEQ_ / 128), 256, 0, stream>>>(
      ybuf, DIM_, Wf1t, DIM_, bf1, nullptr, gbuf, nullptr, nullptr, SEQ_, FFN_, DIM_);
  // FFN2 split-K=2 -> partials (640 blocks), reduce(+bias+residual) -> d_out
  gemm_kernel<EPI_PART><<<dim3(DIM_ / 128, SEQ_ / 128, 2), 256, 0, stream>>>(
      gbuf, FFN_, Wf2t, FFN_, nullptr, nullptr, partF, nullptr, nullptr, SEQ_, DIM_, FFN_ / 2);
  reduce_kernel<<<2048, 256, 0, stream>>>(partF, bf2, hbuf, (float*)d_out);
}

// Round 8
// 520.960 us; speedup vs baseline: 1.1824x; 1.1824x over previous
//
#include <hip/hip_runtime.h>
#include <cstdint>
#include <cstddef>

#define SEQ_ 4096
#define DIM_ 1280
#define NHEAD_ 20
#define HDIM_ 64
#define FFN_ 5120
#define SEG_ 512
#define QKVN_ 3840

typedef __attribute__((ext_vector_type(8))) short bf16x8;
typedef __attribute__((ext_vector_type(4))) float f32x4;
typedef __attribute__((ext_vector_type(8))) unsigned short us8;
typedef __attribute__((ext_vector_type(4))) unsigned short us4;

__device__ __forceinline__ unsigned short f2b(float f) {
  unsigned int u = __builtin_bit_cast(unsigned int, f);
  u += 0x7fffu + ((u >> 16) & 1u);
  return (unsigned short)(u >> 16);
}

__device__ __forceinline__ void gload_lds16(const void* g, void* l) {
  __builtin_amdgcn_global_load_lds(
      (const __attribute__((address_space(1))) unsigned int*)g,
      (__attribute__((address_space(3))) unsigned int*)l, 16, 0, 0);
}

#define WAITVM(N) asm volatile("s_waitcnt vmcnt(" #N ")" ::: "memory")

// ---------- transpose + f32->bf16: out[C][R] = bf16(in[R][C]) ----------
__global__ __launch_bounds__(256) void transp_bf16_kernel(
    const float* __restrict__ in, unsigned short* __restrict__ out, int R, int C) {
  __shared__ float tile[32][33];
  int c0 = blockIdx.x * 32, r0 = blockIdx.y * 32;
  int tx = threadIdx.x & 31, ty = threadIdx.x >> 5;
#pragma unroll
  for (int i = 0; i < 32; i += 8)
    tile[ty + i][tx] = in[(size_t)(r0 + ty + i) * C + c0 + tx];
  __syncthreads();
#pragma unroll
  for (int i = 0; i < 32; i += 8)
    out[(size_t)(c0 + ty + i) * R + r0 + tx] = f2b(tile[tx][ty + i]);
}

// ---------- layernorm f32 -> bf16 ----------
__global__ __launch_bounds__(256) void ln_kernel(
    const float* __restrict__ in, const float* __restrict__ g,
    const float* __restrict__ b, unsigned short* __restrict__ out) {
  int row = blockIdx.x, tid = threadIdx.x;
  int l = tid & 63, w = tid >> 6;
  const float* x = in + (size_t)row * DIM_;
  float v[5], s = 0.f, s2 = 0.f;
#pragma unroll
  for (int i = 0; i < 5; ++i) {
    v[i] = x[tid + i * 256];
    s += v[i];
    s2 += v[i] * v[i];
  }
#pragma unroll
  for (int off = 1; off < 64; off <<= 1) {
    s += __shfl_xor(s, off);
    s2 += __shfl_xor(s2, off);
  }
  __shared__ float red[8];
  if (l == 0) { red[w * 2] = s; red[w * 2 + 1] = s2; }
  __syncthreads();
  s = red[0] + red[2] + red[4] + red[6];
  s2 = red[1] + red[3] + red[5] + red[7];
  float mu = s * (1.f / DIM_);
  float var = s2 * (1.f / DIM_) - mu * mu;
  float rs = rsqrtf(var + 1e-5f);
#pragma unroll
  for (int i = 0; i < 5; ++i) {
    int c = tid + i * 256;
    out[(size_t)row * DIM_ + c] = f2b((v[i] - mu) * rs * g[c] + b[c]);
  }
}

// ---------- 256x256 GEMM body, BK=64, 8 waves, m230-V0-faithful 2-phase ----------
// Guide T3-minimum recipe verbatim: STAGE(next) -> ds_read+MFMA(setprio) ->
// vmcnt(0) -> barrier. One barrier per K-tile. No sched_barrier, no swizzle.
// LDS per buffer: A [row:256][kc:8][16B] 32KB @0, B same @32768 (2 bufs=128KB).
enum { EPI_QKV = 0, EPI_GELU = 3, EPI_PART = 4 };

template <int EPI>
__device__ __forceinline__ void gemm_body(
    const unsigned short* __restrict__ A, int lda,
    const unsigned short* __restrict__ Bt, int ldb,
    const float* __restrict__ bias, const float* __restrict__ bias2,
    void* __restrict__ out0, void* __restrict__ out1, void* __restrict__ out2,
    int M, int N, int Ksub) {
  __shared__ char lds[2][65536];
  const int tid = threadIdx.x;
  const int l = tid & 63, w = tid >> 6;
  const int r16 = l & 15, kg4 = l >> 4;
  const int nwg = gridDim.x * gridDim.y;
  const int orig = blockIdx.y * gridDim.x + blockIdx.x;
  const int swz = (orig & 7) * (nwg >> 3) + (orig >> 3);
  const int m0 = (swz / gridDim.x) * 256, n0 = (swz % gridDim.x) * 256;
  const int wm = (w >> 2) * 128, wn = (w & 3) * 64;
  A += (size_t)blockIdx.z * Ksub;
  Bt += (size_t)blockIdx.z * Ksub;
  // coalesced staging: lane covers (row = w*8 + l/8 [+ g*64], kc = l&7)
  const unsigned short* aA = A + (size_t)(m0 + w * 8 + (l >> 3)) * lda + (l & 7) * 8;
  const unsigned short* aB = Bt + (size_t)(n0 + w * 8 + (l >> 3)) * ldb + (l & 7) * 8;

  f32x4 acc[8][4] = {};
  const int nt = Ksub >> 6;

#define STAGE(b, kt_)                                                     \
  do {                                                                    \
    const size_t kb = (size_t)(kt_) * 64;                                 \
    char* dA = &lds[b][0] + (w * 64) * 16;                                \
    char* dB = dA + 32768;                                                \
    _Pragma("unroll") for (int g = 0; g < 4; ++g) {                       \
      gload_lds16(aA + (size_t)(g * 64) * lda + kb, dA + g * 8192);       \
      gload_lds16(aB + (size_t)(g * 64) * ldb + kb, dB + g * 8192);       \
    }                                                                     \
  } while (0)

  STAGE(0, 0);
  WAITVM(0);
  __builtin_amdgcn_s_barrier();

#pragma unroll 1
  for (int t = 0; t < nt; ++t) {
    if (t + 1 < nt) STAGE((t + 1) & 1, t + 1);
    const char* sA = &lds[t & 1][0];
    const char* sB = sA + 32768;
#pragma unroll
    for (int kk = 0; kk < 2; ++kk) {
      bf16x8 af[8], bfv[4];
#pragma unroll
      for (int mi = 0; mi < 8; ++mi)
        af[mi] = *(const bf16x8*)(sA + ((wm + mi * 16 + r16) * 8 + kk * 4 + kg4) * 16);
#pragma unroll
      for (int ni = 0; ni < 4; ++ni)
        bfv[ni] = *(const bf16x8*)(sB + ((wn + ni * 16 + r16) * 8 + kk * 4 + kg4) * 16);
      __builtin_amdgcn_s_setprio(1);
#pragma unroll
      for (int mi = 0; mi < 8; ++mi)
#pragma unroll
        for (int ni = 0; ni < 4; ++ni)
          acc[mi][ni] = __builtin_amdgcn_mfma_f32_16x16x32_bf16(af[mi], bfv[ni], acc[mi][ni], 0, 0, 0);
      __builtin_amdgcn_s_setprio(0);
    }
    WAITVM(0);
    __builtin_amdgcn_s_barrier();
  }
#undef STAGE

  const int rg = kg4 * 4;
#pragma unroll
  for (int mi = 0; mi < 8; ++mi) {
#pragma unroll
    for (int ni = 0; ni < 4; ++ni) {
      int row = m0 + wm + mi * 16 + rg;
      int col = n0 + wn + ni * 16 + r16;
      f32x4 v = acc[mi][ni];
      if constexpr (EPI == EPI_QKV) {
        if (col < DIM_) {  // Q (+bq)
          unsigned short* O = (unsigned short*)out0;
          float bb = bias[col];
#pragma unroll
        for (int j = 0; j < 4; ++j) O[(size_t)(row + j) * DIM_ + col] = f2b(v[j] + bb);
        } else if (col < 2 * DIM_) {  // K (no bias)
          unsigned short* O = (unsigned short*)out1;
          int cc = col - DIM_;
#pragma unroll
          for (int j = 0; j < 4; ++j) O[(size_t)(row + j) * DIM_ + cc] = f2b(v[j]);
        } else {  // V (+bv), transposed store -> Vt[d][s]
          unsigned short* O = (unsigned short*)out2;
          int cc = col - 2 * DIM_;
          float bb = bias2[cc];
          us4 pk;
#pragma unroll
          for (int j = 0; j < 4; ++j) pk[j] = f2b(v[j] + bb);
          *(us4*)(O + (size_t)cc * SEQ_ + row) = pk;
        }
      } else if constexpr (EPI == EPI_GELU) {
        unsigned short* O = (unsigned short*)out0;
        float bb = bias[col];
#pragma unroll
        for (int j = 0; j < 4; ++j) {
          float t = v[j] + bb;
          t = 0.5f * t * (1.f + erff(t * 0.70710678118f));
          O[(size_t)(row + j) * N + col] = f2b(t);
        }
      } else {  // EPI_PART: raw f32 partial per K-split
        float* O = (float*)out0 + (size_t)blockIdx.z * M * N;
#pragma unroll
        for (int j = 0; j < 4; ++j) O[(size_t)(row + j) * N + col] = v[j];
      }
    }
  }
}

// distinct names for rocprof attribution
__global__ __launch_bounds__(512, 2) void qkv_gemm(
    const unsigned short* A, const unsigned short* Bt, const float* bq,
    const float* bv, void* q, void* k, void* v) {
  gemm_body<EPI_QKV>(A, DIM_, Bt, DIM_, bq, bv, q, k, v, SEQ_, QKVN_, DIM_);
}
__global__ __launch_bounds__(512, 2) void wo_gemm(
    const unsigned short* A, const unsigned short* Bt, void* part) {
  gemm_body<EPI_PART>(A, DIM_, Bt, DIM_, nullptr, nullptr, part, nullptr, nullptr,
                      SEQ_, DIM_, DIM_ / 2);
}
__global__ __launch_bounds__(512, 2) void ffn1_gemm(
    const unsigned short* A, const unsigned short* Bt, const float* bf1, void* g) {
  gemm_body<EPI_GELU>(A, DIM_, Bt, DIM_, bf1, nullptr, g, nullptr, nullptr,
                      SEQ_, FFN_, DIM_);
}
__global__ __launch_bounds__(512, 2) void ffn2_gemm(
    const unsigned short* A, const unsigned short* Bt, void* part) {
  gemm_body<EPI_PART>(A, FFN_, Bt, FFN_, nullptr, nullptr, part, nullptr, nullptr,
                      SEQ_, DIM_, FFN_ / 2);
}

// ---------- split-K reduce: out = p0 + p1 + bias + res (f32) ----------
__global__ __launch_bounds__(256) void reduce_kernel(
    const float* __restrict__ part, const float* __restrict__ bias,
    const float* __restrict__ res, float* __restrict__ out) {
  const size_t MN = (size_t)SEQ_ * DIM_;
  for (size_t i = blockIdx.x * 256 + threadIdx.x; i * 4 < MN; i += (size_t)gridDim.x * 256) {
    size_t e = i * 4;
    f32x4 a = *(const f32x4*)(part + e);
    f32x4 b = *(const f32x4*)(part + MN + e);
    f32x4 r = *(const f32x4*)(res + e);
    f32x4 bb = *(const f32x4*)(bias + (int)(e % DIM_));
    f32x4 o = a + b + r + bb;
    *(f32x4*)(out + e) = o;
  }
}

// ---------- attention: per (head, seg, 64-row q chunk) ----------
__global__ __launch_bounds__(256) void attn_kernel(
    const unsigned short* __restrict__ Q, const unsigned short* __restrict__ Kb,
    const unsigned short* __restrict__ Vt, unsigned short* __restrict__ O) {
  __shared__ float S[64][512];
  int tid = threadIdx.x;
  int l = tid & 63, w = tid >> 6;
  int orig = blockIdx.x;
  int b = (orig & 7) * (gridDim.x >> 3) + (orig >> 3);
  int qc = b & 7, seg = (b >> 3) & 7, hh = b >> 6;
  int r16 = l & 15, kg = l >> 4, rg = (l >> 4) * 4;
  int qrow0 = seg * SEG_ + qc * 64 + w * 16;
  bf16x8 aq[2];
#pragma unroll
  for (int ks = 0; ks < 2; ++ks)
    aq[ks] = *(const bf16x8*)(Q + (size_t)(qrow0 + r16) * DIM_ + hh * HDIM_ + ks * 32 + kg * 8);
#pragma unroll 4
  for (int kc = 0; kc < 32; ++kc) {
    f32x4 acc = {};
#pragma unroll
    for (int ks = 0; ks < 2; ++ks) {
      bf16x8 bk = *(const bf16x8*)(Kb + (size_t)(seg * SEG_ + kc * 16 + r16) * DIM_ +
                                   hh * HDIM_ + ks * 32 + kg * 8);
      acc = __builtin_amdgcn_mfma_f32_16x16x32_bf16(aq[ks], bk, acc, 0, 0, 0);
    }
#pragma unroll
    for (int j = 0; j < 4; ++j)
      S[w * 16 + rg + j][kc * 16 + r16] = acc[j] * 0.125f;
  }
#pragma unroll 2
  for (int r = 0; r < 16; ++r) {
    float* Sr = &S[w * 16 + r][0];
    f32x4 v0 = *(const f32x4*)(Sr + l * 8);
    f32x4 v1 = *(const f32x4*)(Sr + l * 8 + 4);
    float m = fmaxf(fmaxf(fmaxf(v0[0], v0[1]), fmaxf(v0[2], v0[3])),
                    fmaxf(fmaxf(v1[0], v1[1]), fmaxf(v1[2], v1[3])));
#pragma unroll
    for (int off = 1; off < 64; off <<= 1) m = fmaxf(m, __shfl_xor(m, off));
    float ev[8];
    ev[0] = v0[0]; ev[1] = v0[1]; ev[2] = v0[2]; ev[3] = v0[3];
    ev[4] = v1[0]; ev[5] = v1[1]; ev[6] = v1[2]; ev[7] = v1[3];
    float sum = 0.f;
#pragma unroll
    for (int j = 0; j < 8; ++j) { ev[j] = __expf(ev[j] - m); sum += ev[j]; }
#pragma unroll
    for (int off = 1; off < 64; off <<= 1) sum += __shfl_xor(sum, off);
    float inv = 1.f / sum;
    us8 pk;
#pragma unroll
    for (int j = 0; j < 8; ++j) pk[j] = f2b(ev[j] * inv);
    *(us8*)((unsigned short*)Sr + ((l ^ (r & 7)) * 8)) = pk;
  }
  f32x4 oacc[4] = {};
  const unsigned short* Pr = (const unsigned short*)&S[w * 16 + r16][0];
  int rowx = r16 & 7;
#pragma unroll 2
  for (int ks = 0; ks < 16; ++ks) {
    int chunk = (ks * 4 + kg) ^ rowx;
    bf16x8 pa = *(const bf16x8*)(Pr + chunk * 8);
#pragma unroll
    for (int df = 0; df < 4; ++df) {
      bf16x8 bv = *(const bf16x8*)(Vt + (size_t)(hh * HDIM_ + df * 16 + r16) * SEQ_ +
                                   seg * SEG_ + ks * 32 + kg * 8);
      oacc[df] = __builtin_amdgcn_mfma_f32_16x16x32_bf16(pa, bv, oacc[df], 0, 0, 0);
    }
  }
#pragma unroll
  for (int df = 0; df < 4; ++df)
#pragma unroll
    for (int j = 0; j < 4; ++j)
      O[(size_t)(qrow0 + rg + j) * DIM_ + hh * HDIM_ + df * 16 + r16] = f2b(oacc[df][j]);
}

extern "C" void kernel_launch(void* const* d_in, const int* in_sizes, int n_in,
                              void* d_out, int out_size, void* d_ws, size_t ws_size,
                              hipStream_t stream) {
  (void)in_sizes; (void)n_in; (void)out_size; (void)ws_size;
  const float* hidden = (const float*)d_in[0];
  const float* Wq = (const float*)d_in[2];
  const float* bq = (const float*)d_in[3];
  const float* Wk = (const float*)d_in[4];
  const float* Wv = (const float*)d_in[5];
  const float* bv = (const float*)d_in[6];
  const float* Wo = (const float*)d_in[7];
  const float* bo = (const float*)d_in[8];
  const float* g1 = (const float*)d_in[9];
  const float* b1 = (const float*)d_in[10];
  const float* Wf1 = (const float*)d_in[11];
  const float* bf1 = (const float*)d_in[12];
  const float* Wf2 = (const float*)d_in[13];
  const float* bf2 = (const float*)d_in[14];
  const float* g2 = (const float*)d_in[15];
  const float* b2 = (const float*)d_in[16];

  char* p = (char*)d_ws;
  auto alloc = [&](size_t bytes) {
    char* r = p;
    p += (bytes + 255) & ~(size_t)255;
    return r;
  };
  unsigned short* xln   = (unsigned short*)alloc((size_t)SEQ_ * DIM_ * 2);
  unsigned short* Wqkvt = (unsigned short*)alloc((size_t)DIM_ * QKVN_ * 2);
  unsigned short* Wot   = (unsigned short*)alloc((size_t)DIM_ * DIM_ * 2);
  unsigned short* Wf1t  = (unsigned short*)alloc((size_t)DIM_ * FFN_ * 2);
  unsigned short* Wf2t  = (unsigned short*)alloc((size_t)DIM_ * FFN_ * 2);
  unsigned short* Qb    = (unsigned short*)alloc((size_t)SEQ_ * DIM_ * 2);
  unsigned short* Kbf   = (unsigned short*)alloc((size_t)SEQ_ * DIM_ * 2);
  unsigned short* Vtb   = (unsigned short*)alloc((size_t)SEQ_ * DIM_ * 2);
  unsigned short* attnb = (unsigned short*)alloc((size_t)SEQ_ * DIM_ * 2);
  float*          hbuf  = (float*)alloc((size_t)SEQ_ * DIM_ * 4);
  unsigned short* ybuf  = (unsigned short*)alloc((size_t)SEQ_ * DIM_ * 2);
  unsigned short* gbuf  = (unsigned short*)alloc((size_t)SEQ_ * FFN_ * 2);
  // Wo partials (2 x SEQ*DIM f32 = 41.9MB) alias gbuf (41.9MB, not yet live);
  // FFN2 partials alias Qb..attnb (4 x SEQ*DIM bf16 = 41.9MB, dead after Wo).
  float* partW = (float*)gbuf;
  float* partF = (float*)Qb;

  transp_bf16_kernel<<<dim3(DIM_ / 32, DIM_ / 32), 256, 0, stream>>>(Wq, Wqkvt, DIM_, DIM_);
  transp_bf16_kernel<<<dim3(DIM_ / 32, DIM_ / 32), 256, 0, stream>>>(Wk, Wqkvt + (size_t)DIM_ * DIM_, DIM_, DIM_);
  transp_bf16_kernel<<<dim3(DIM_ / 32, DIM_ / 32), 256, 0, stream>>>(Wv, Wqkvt + (size_t)2 * DIM_ * DIM_, DIM_, DIM_);
  transp_bf16_kernel<<<dim3(DIM_ / 32, DIM_ / 32), 256, 0, stream>>>(Wo, Wot, DIM_, DIM_);
  transp_bf16_kernel<<<dim3(FFN_ / 32, DIM_ / 32), 256, 0, stream>>>(Wf1, Wf1t, DIM_, FFN_);
  transp_bf16_kernel<<<dim3(DIM_ / 32, FFN_ / 32), 256, 0, stream>>>(Wf2, Wf2t, FFN_, DIM_);
  ln_kernel<<<SEQ_, 256, 0, stream>>>(hidden, g1, b1, xln);
  // fused QKV projection: 240 blocks, 20 K-steps
  qkv_gemm<<<dim3(QKVN_ / 256, SEQ_ / 256), 512, 0, stream>>>(
      xln, Wqkvt, bq, bv, Qb, Kbf, Vtb);
  attn_kernel<<<NHEAD_ * 8 * 8, 256, 0, stream>>>(Qb, Kbf, Vtb, attnb);
  // Wo split-K=2: 160 blocks, 10 K-steps -> partials; reduce adds bias+residual
  wo_gemm<<<dim3(DIM_ / 256, SEQ_ / 256, 2), 512, 0, stream>>>(attnb, Wot, partW);
  reduce_kernel<<<2048, 256, 0, stream>>>(partW, bo, hidden, hbuf);
  ln_kernel<<<SEQ_, 256, 0, stream>>>(hbuf, g2, b2, ybuf);
  // FFN1 + GELU: 320 blocks, 20 K-steps
  ffn1_gemm<<<dim3(FFN_ / 256, SEQ_ / 256), 512, 0, stream>>>(ybuf, Wf1t, bf1, gbuf);
  // FFN2 split-K=2: 160 blocks, 40 K-steps -> partials; reduce -> d_out
  ffn2_gemm<<<dim3(DIM_ / 256, SEQ_ / 256, 2), 512, 0, stream>>>(gbuf, Wf2t, partF);
  reduce_kernel<<<2048, 256, 0, stream>>>(partF, bf2, hbuf, (float*)d_out);
}

// Round 9
// 418.453 us; speedup vs baseline: 1.4720x; 1.2450x over previous
//
#include <hip/hip_runtime.h>
#include <cstdint>
#include <cstddef>

#define SEQ_ 4096
#define DIM_ 1280
#define NHEAD_ 20
#define HDIM_ 64
#define FFN_ 5120
#define SEG_ 512
#define QKVN_ 3840

typedef __attribute__((ext_vector_type(8))) short bf16x8;
typedef __attribute__((ext_vector_type(4))) float f32x4;
typedef __attribute__((ext_vector_type(8))) unsigned short us8;
typedef __attribute__((ext_vector_type(4))) unsigned short us4;

__device__ __forceinline__ unsigned short f2b(float f) {
  unsigned int u = __builtin_bit_cast(unsigned int, f);
  u += 0x7fffu + ((u >> 16) & 1u);
  return (unsigned short)(u >> 16);
}

__device__ __forceinline__ void gload_lds16(const void* g, void* l) {
  __builtin_amdgcn_global_load_lds(
      (const __attribute__((address_space(1))) unsigned int*)g,
      (__attribute__((address_space(3))) unsigned int*)l, 16, 0, 0);
}

#define WAITVM(N) asm volatile("s_waitcnt vmcnt(" #N ")" ::: "memory")

// ---------- transpose + f32->bf16: out[C][R] = bf16(in[R][C]) ----------
__global__ __launch_bounds__(256) void transp_bf16_kernel(
    const float* __restrict__ in, unsigned short* __restrict__ out, int R, int C) {
  __shared__ float tile[32][33];
  int c0 = blockIdx.x * 32, r0 = blockIdx.y * 32;
  int tx = threadIdx.x & 31, ty = threadIdx.x >> 5;
#pragma unroll
  for (int i = 0; i < 32; i += 8)
    tile[ty + i][tx] = in[(size_t)(r0 + ty + i) * C + c0 + tx];
  __syncthreads();
#pragma unroll
  for (int i = 0; i < 32; i += 8)
    out[(size_t)(c0 + ty + i) * R + r0 + tx] = f2b(tile[tx][ty + i]);
}

// ---------- layernorm f32 -> bf16 ----------
__global__ __launch_bounds__(256) void ln_kernel(
    const float* __restrict__ in, const float* __restrict__ g,
    const float* __restrict__ b, unsigned short* __restrict__ out) {
  int row = blockIdx.x, tid = threadIdx.x;
  int l = tid & 63, w = tid >> 6;
  const float* x = in + (size_t)row * DIM_;
  float v[5], s = 0.f, s2 = 0.f;
#pragma unroll
  for (int i = 0; i < 5; ++i) {
    v[i] = x[tid + i * 256];
    s += v[i];
    s2 += v[i] * v[i];
  }
#pragma unroll
  for (int off = 1; off < 64; off <<= 1) {
    s += __shfl_xor(s, off);
    s2 += __shfl_xor(s2, off);
  }
  __shared__ float red[8];
  if (l == 0) { red[w * 2] = s; red[w * 2 + 1] = s2; }
  __syncthreads();
  s = red[0] + red[2] + red[4] + red[6];
  s2 = red[1] + red[3] + red[5] + red[7];
  float mu = s * (1.f / DIM_);
  float var = s2 * (1.f / DIM_) - mu * mu;
  float rs = rsqrtf(var + 1e-5f);
#pragma unroll
  for (int i = 0; i < 5; ++i) {
    int c = tid + i * 256;
    out[(size_t)row * DIM_ + c] = f2b((v[i] - mu) * rs * g[c] + b[c]);
  }
}

// ---------- 128x256 GEMM, BK=32, 8 waves (64x64/wave), 2-phase dbuf ----------
// LDS/buf 24KB: A [128r][4c][16B] @0 (8KB), B [256r][4c][16B] @8192 (16KB).
// XOR swizzle: logical chunk kc at phys cp = kc ^ (row&3) -- applied on the
// staging SOURCE (linear gload dest, rule #21) and on ds_read -> <=2-way free.
// M-band XCD map: by = xcd*(ny/8)+idx/nx -> A-band L2-resident per XCD.
// 2 blocks/CU (48KB LDS, VGPR<=128 via launch_bounds(512,4)).
enum { EPI_QKV = 0, EPI_GELU = 3, EPI_PART = 4 };

template <int EPI>
__device__ __forceinline__ void gemm_body(
    const unsigned short* __restrict__ A, int lda,
    const unsigned short* __restrict__ Bt, int ldb,
    const float* __restrict__ bias, const float* __restrict__ bias2,
    void* __restrict__ out0, void* __restrict__ out1, void* __restrict__ out2,
    int M, int N, int K, int nz) {
  __shared__ char lds[2][24576];
  const int tid = threadIdx.x;
  const int l = tid & 63, w = tid >> 6;
  const int r16 = l & 15, kg4 = l >> 4;
  // M-band XCD swizzle (ny always 32 here; band = 4)
  const int nx = gridDim.x;
  const int orig = blockIdx.y * nx + blockIdx.x;
  const int xcd = orig & 7, idx = orig >> 3;
  const int by = xcd * (gridDim.y >> 3) + idx / nx;
  const int bx = idx % nx;
  const int m0 = by * 128, n0 = bx * 256;
  const int wm = (w >> 2) * 64, wn = (w & 3) * 64;
  // split-K (uneven): z in [0,nz)
  const int z = blockIdx.z;
  const int ntK = K >> 5;
  const int base = ntK / nz, rem = ntK % nz;
  const int k0 = z * base + (z < rem ? z : rem);
  const int nt = base + (z < rem ? 1 : 0);
  // staging sources, pre-swizzled chunk: kc = (t&3) ^ ((t>>2)&3)
  const int cp = tid & 3, rsub = (tid >> 2) & 3;
  const int kc = cp ^ rsub;
  const unsigned short* aA = A + (size_t)(m0 + (tid >> 2)) * lda + kc * 8 + k0 * 32;
  const unsigned short* aB = Bt + (size_t)(n0 + (tid >> 2)) * ldb + kc * 8 + k0 * 32;
  const unsigned short* aB1 = aB + (size_t)128 * ldb;
  // swizzled fragment read offsets
  const int cswz = (kg4 ^ (r16 & 3)) << 4;
  int aoff[4], boff[4];
#pragma unroll
  for (int mi = 0; mi < 4; ++mi) aoff[mi] = (wm + mi * 16 + r16) * 64 + cswz;
#pragma unroll
  for (int ni = 0; ni < 4; ++ni) boff[ni] = 8192 + (wn + ni * 16 + r16) * 64 + cswz;

  f32x4 acc[4][4] = {};

#define STAGE(b, kt_)                                          \
  do {                                                         \
    const int kb = (kt_) * 32;                                 \
    char* dA = &lds[b][0] + w * 1024;                          \
    char* dB = &lds[b][0] + 8192 + w * 1024;                   \
    gload_lds16(aA + kb, dA);                                  \
    gload_lds16(aB + kb, dB);                                  \
    gload_lds16(aB1 + kb, dB + 8192);                          \
  } while (0)

  STAGE(0, 0);
  WAITVM(0);
  __builtin_amdgcn_s_barrier();

#pragma unroll 1
  for (int t = 0; t < nt; ++t) {
    if (t + 1 < nt) STAGE((t + 1) & 1, t + 1);
    const char* sl = &lds[t & 1][0];
    bf16x8 af[4], bfv[4];
#pragma unroll
    for (int mi = 0; mi < 4; ++mi) af[mi] = *(const bf16x8*)(sl + aoff[mi]);
#pragma unroll
    for (int ni = 0; ni < 4; ++ni) bfv[ni] = *(const bf16x8*)(sl + boff[ni]);
    __builtin_amdgcn_s_setprio(1);
#pragma unroll
    for (int mi = 0; mi < 4; ++mi)
#pragma unroll
      for (int ni = 0; ni < 4; ++ni)
        acc[mi][ni] = __builtin_amdgcn_mfma_f32_16x16x32_bf16(af[mi], bfv[ni], acc[mi][ni], 0, 0, 0);
    __builtin_amdgcn_s_setprio(0);
    WAITVM(0);
    __builtin_amdgcn_s_barrier();
  }
#undef STAGE

  const int rg = kg4 * 4;
#pragma unroll
  for (int mi = 0; mi < 4; ++mi) {
#pragma unroll
    for (int ni = 0; ni < 4; ++ni) {
      int row = m0 + wm + mi * 16 + rg;
      int col = n0 + wn + ni * 16 + r16;
      f32x4 v = acc[mi][ni];
      if constexpr (EPI == EPI_QKV) {
        if (col < DIM_) {  // Q (+bq)
          unsigned short* O = (unsigned short*)out0;
          float bb = bias[col];
#pragma unroll
          for (int j = 0; j < 4; ++j) O[(size_t)(row + j) * DIM_ + col] = f2b(v[j] + bb);
        } else if (col < 2 * DIM_) {  // K (no bias)
          unsigned short* O = (unsigned short*)out1;
          int cc = col - DIM_;
#pragma unroll
          for (int j = 0; j < 4; ++j) O[(size_t)(row + j) * DIM_ + cc] = f2b(v[j]);
        } else {  // V (+bv), transposed store -> Vt[d][s]
          unsigned short* O = (unsigned short*)out2;
          int cc = col - 2 * DIM_;
          float bb = bias2[cc];
          us4 pk;
#pragma unroll
          for (int j = 0; j < 4; ++j) pk[j] = f2b(v[j] + bb);
          *(us4*)(O + (size_t)cc * SEQ_ + row) = pk;
        }
      } else if constexpr (EPI == EPI_GELU) {
        unsigned short* O = (unsigned short*)out0;
        float bb = bias[col];
#pragma unroll
        for (int j = 0; j < 4; ++j) {
          float t = v[j] + bb;
          t = 0.5f * t * (1.f + erff(t * 0.70710678118f));
          O[(size_t)(row + j) * N + col] = f2b(t);
        }
      } else {  // EPI_PART: raw f32 partial per K-split
        float* O = (float*)out0 + (size_t)blockIdx.z * M * N;
#pragma unroll
        for (int j = 0; j < 4; ++j) O[(size_t)(row + j) * N + col] = v[j];
      }
    }
  }
}

// distinct names for rocprof attribution
__global__ __launch_bounds__(512, 4) void qkv_gemm(
    const unsigned short* A, const unsigned short* Bt, const float* bq,
    const float* bv, void* q, void* k, void* v) {
  gemm_body<EPI_QKV>(A, DIM_, Bt, DIM_, bq, bv, q, k, v, SEQ_, QKVN_, DIM_, 1);
}
__global__ __launch_bounds__(512, 4) void wo_gemm(
    const unsigned short* A, const unsigned short* Bt, void* part) {
  gemm_body<EPI_PART>(A, DIM_, Bt, DIM_, nullptr, nullptr, part, nullptr, nullptr,
                      SEQ_, DIM_, DIM_, 3);
}
__global__ __launch_bounds__(512, 4) void ffn1_gemm(
    const unsigned short* A, const unsigned short* Bt, const float* bf1, void* g) {
  gemm_body<EPI_GELU>(A, DIM_, Bt, DIM_, bf1, nullptr, g, nullptr, nullptr,
                      SEQ_, FFN_, DIM_, 1);
}
__global__ __launch_bounds__(512, 4) void ffn2_gemm(
    const unsigned short* A, const unsigned short* Bt, void* part) {
  gemm_body<EPI_PART>(A, FFN_, Bt, FFN_, nullptr, nullptr, part, nullptr, nullptr,
                      SEQ_, DIM_, FFN_, 3);
}

// ---------- split-K reduce (3-way): out = p0+p1+p2 + bias + res ----------
__global__ __launch_bounds__(256) void reduce3_kernel(
    const float* __restrict__ part, const float* __restrict__ bias,
    const float* __restrict__ res, float* __restrict__ out) {
  const size_t MN = (size_t)SEQ_ * DIM_;
  for (size_t i = blockIdx.x * 256 + threadIdx.x; i * 4 < MN; i += (size_t)gridDim.x * 256) {
    size_t e = i * 4;
    f32x4 a = *(const f32x4*)(part + e);
    f32x4 b = *(const f32x4*)(part + MN + e);
    f32x4 c = *(const f32x4*)(part + 2 * MN + e);
    f32x4 r = *(const f32x4*)(res + e);
    f32x4 bb = *(const f32x4*)(bias + (int)(e % DIM_));
    f32x4 o = a + b + c + r + bb;
    *(f32x4*)(out + e) = o;
  }
}

// ---------- attention: per (head, seg, 64-row q chunk) ----------
__global__ __launch_bounds__(256) void attn_kernel(
    const unsigned short* __restrict__ Q, const unsigned short* __restrict__ Kb,
    const unsigned short* __restrict__ Vt, unsigned short* __restrict__ O) {
  __shared__ float S[64][512];
  int tid = threadIdx.x;
  int l = tid & 63, w = tid >> 6;
  int orig = blockIdx.x;
  int b = (orig & 7) * (gridDim.x >> 3) + (orig >> 3);
  int qc = b & 7, seg = (b >> 3) & 7, hh = b >> 6;
  int r16 = l & 15, kg = l >> 4, rg = (l >> 4) * 4;
  int qrow0 = seg * SEG_ + qc * 64 + w * 16;
  bf16x8 aq[2];
#pragma unroll
  for (int ks = 0; ks < 2; ++ks)
    aq[ks] = *(const bf16x8*)(Q + (size_t)(qrow0 + r16) * DIM_ + hh * HDIM_ + ks * 32 + kg * 8);
#pragma unroll 4
  for (int kc = 0; kc < 32; ++kc) {
    f32x4 acc = {};
#pragma unroll
    for (int ks = 0; ks < 2; ++ks) {
      bf16x8 bk = *(const bf16x8*)(Kb + (size_t)(seg * SEG_ + kc * 16 + r16) * DIM_ +
                                   hh * HDIM_ + ks * 32 + kg * 8);
      acc = __builtin_amdgcn_mfma_f32_16x16x32_bf16(aq[ks], bk, acc, 0, 0, 0);
    }
#pragma unroll
    for (int j = 0; j < 4; ++j)
      S[w * 16 + rg + j][kc * 16 + r16] = acc[j] * 0.125f;
  }
#pragma unroll 2
  for (int r = 0; r < 16; ++r) {
    float* Sr = &S[w * 16 + r][0];
    f32x4 v0 = *(const f32x4*)(Sr + l * 8);
    f32x4 v1 = *(const f32x4*)(Sr + l * 8 + 4);
    float m = fmaxf(fmaxf(fmaxf(v0[0], v0[1]), fmaxf(v0[2], v0[3])),
                    fmaxf(fmaxf(v1[0], v1[1]), fmaxf(v1[2], v1[3])));
#pragma unroll
    for (int off = 1; off < 64; off <<= 1) m = fmaxf(m, __shfl_xor(m, off));
    float ev[8];
    ev[0] = v0[0]; ev[1] = v0[1]; ev[2] = v0[2]; ev[3] = v0[3];
    ev[4] = v1[0]; ev[5] = v1[1]; ev[6] = v1[2]; ev[7] = v1[3];
    float sum = 0.f;
#pragma unroll
    for (int j = 0; j < 8; ++j) { ev[j] = __expf(ev[j] - m); sum += ev[j]; }
#pragma unroll
    for (int off = 1; off < 64; off <<= 1) sum += __shfl_xor(sum, off);
    float inv = 1.f / sum;
    us8 pk;
#pragma unroll
    for (int j = 0; j < 8; ++j) pk[j] = f2b(ev[j] * inv);
    *(us8*)((unsigned short*)Sr + ((l ^ (r & 7)) * 8)) = pk;
  }
  f32x4 oacc[4] = {};
  const unsigned short* Pr = (const unsigned short*)&S[w * 16 + r16][0];
  int rowx = r16 & 7;
#pragma unroll 2
  for (int ks = 0; ks < 16; ++ks) {
    int chunk = (ks * 4 + kg) ^ rowx;
    bf16x8 pa = *(const bf16x8*)(Pr + chunk * 8);
#pragma unroll
    for (int df = 0; df < 4; ++df) {
      bf16x8 bv = *(const bf16x8*)(Vt + (size_t)(hh * HDIM_ + df * 16 + r16) * SEQ_ +
                                   seg * SEG_ + ks * 32 + kg * 8);
      oacc[df] = __builtin_amdgcn_mfma_f32_16x16x32_bf16(pa, bv, oacc[df], 0, 0, 0);
    }
  }
#pragma unroll
  for (int df = 0; df < 4; ++df)
#pragma unroll
    for (int j = 0; j < 4; ++j)
      O[(size_t)(qrow0 + rg + j) * DIM_ + hh * HDIM_ + df * 16 + r16] = f2b(oacc[df][j]);
}

extern "C" void kernel_launch(void* const* d_in, const int* in_sizes, int n_in,
                              void* d_out, int out_size, void* d_ws, size_t ws_size,
                              hipStream_t stream) {
  (void)in_sizes; (void)n_in; (void)out_size; (void)ws_size;
  const float* hidden = (const float*)d_in[0];
  const float* Wq = (const float*)d_in[2];
  const float* bq = (const float*)d_in[3];
  const float* Wk = (const float*)d_in[4];
  const float* Wv = (const float*)d_in[5];
  const float* bv = (const float*)d_in[6];
  const float* Wo = (const float*)d_in[7];
  const float* bo = (const float*)d_in[8];
  const float* g1 = (const float*)d_in[9];
  const float* b1 = (const float*)d_in[10];
  const float* Wf1 = (const float*)d_in[11];
  const float* bf1 = (const float*)d_in[12];
  const float* Wf2 = (const float*)d_in[13];
  const float* bf2 = (const float*)d_in[14];
  const float* g2 = (const float*)d_in[15];
  const float* b2 = (const float*)d_in[16];

  char* p = (char*)d_ws;
  auto alloc = [&](size_t bytes) {
    char* r = p;
    p += (bytes + 255) & ~(size_t)255;
    return r;
  };
  unsigned short* xln   = (unsigned short*)alloc((size_t)SEQ_ * DIM_ * 2);
  unsigned short* Wqkvt = (unsigned short*)alloc((size_t)DIM_ * QKVN_ * 2);
  unsigned short* Wot   = (unsigned short*)alloc((size_t)DIM_ * DIM_ * 2);
  unsigned short* Wf1t  = (unsigned short*)alloc((size_t)DIM_ * FFN_ * 2);
  unsigned short* Wf2t  = (unsigned short*)alloc((size_t)DIM_ * FFN_ * 2);
  unsigned short* Qb    = (unsigned short*)alloc((size_t)SEQ_ * DIM_ * 2);
  unsigned short* Kbf   = (unsigned short*)alloc((size_t)SEQ_ * DIM_ * 2);
  unsigned short* Vtb   = (unsigned short*)alloc((size_t)SEQ_ * DIM_ * 2);
  unsigned short* attnb = (unsigned short*)alloc((size_t)SEQ_ * DIM_ * 2);
  float*          hbuf  = (float*)alloc((size_t)SEQ_ * DIM_ * 4);
  unsigned short* ybuf  = (unsigned short*)alloc((size_t)SEQ_ * DIM_ * 2);
  unsigned short* gbuf  = (unsigned short*)alloc((size_t)SEQ_ * FFN_ * 2);
  float*          part3 = (float*)alloc((size_t)3 * SEQ_ * DIM_ * 4);

  transp_bf16_kernel<<<dim3(DIM_ / 32, DIM_ / 32), 256, 0, stream>>>(Wq, Wqkvt, DIM_, DIM_);
  transp_bf16_kernel<<<dim3(DIM_ / 32, DIM_ / 32), 256, 0, stream>>>(Wk, Wqkvt + (size_t)DIM_ * DIM_, DIM_, DIM_);
  transp_bf16_kernel<<<dim3(DIM_ / 32, DIM_ / 32), 256, 0, stream>>>(Wv, Wqkvt + (size_t)2 * DIM_ * DIM_, DIM_, DIM_);
  transp_bf16_kernel<<<dim3(DIM_ / 32, DIM_ / 32), 256, 0, stream>>>(Wo, Wot, DIM_, DIM_);
  transp_bf16_kernel<<<dim3(FFN_ / 32, DIM_ / 32), 256, 0, stream>>>(Wf1, Wf1t, DIM_, FFN_);
  transp_bf16_kernel<<<dim3(DIM_ / 32, FFN_ / 32), 256, 0, stream>>>(Wf2, Wf2t, FFN_, DIM_);
  ln_kernel<<<SEQ_, 256, 0, stream>>>(hidden, g1, b1, xln);
  // QKV: 15x32 = 480 blocks, single round at 2 blocks/CU
  qkv_gemm<<<dim3(QKVN_ / 256, SEQ_ / 128), 512, 0, stream>>>(
      xln, Wqkvt, bq, bv, Qb, Kbf, Vtb);
  attn_kernel<<<NHEAD_ * 8 * 8, 256, 0, stream>>>(Qb, Kbf, Vtb, attnb);
  // Wo split-K=3: 5x32x3 = 480 blocks; reduce adds bias+residual
  wo_gemm<<<dim3(DIM_ / 256, SEQ_ / 128, 3), 512, 0, stream>>>(attnb, Wot, part3);
  reduce3_kernel<<<2048, 256, 0, stream>>>(part3, bo, hidden, hbuf);
  ln_kernel<<<SEQ_, 256, 0, stream>>>(hbuf, g2, b2, ybuf);
  // FFN1 + GELU: 20x32 = 640 blocks
  ffn1_gemm<<<dim3(FFN_ / 256, SEQ_ / 128), 512, 0, stream>>>(ybuf, Wf1t, bf1, gbuf);
  // FFN2 split-K=3: 5x32x3 = 480 blocks; reduce -> d_out
  ffn2_gemm<<<dim3(DIM_ / 256, SEQ_ / 128, 3), 512, 0, stream>>>(gbuf, Wf2t, part3);
  reduce3_kernel<<<2048, 256, 0, stream>>>(part3, bf2, hbuf, (float*)d_out);
}

// Round 10
// 413.050 us; speedup vs baseline: 1.4913x; 1.0131x over previous
//
#include <hip/hip_runtime.h>
#include <cstdint>
#include <cstddef>

#define SEQ_ 4096
#define DIM_ 1280
#define NHEAD_ 20
#define HDIM_ 64
#define FFN_ 5120
#define SEG_ 512
#define QKVN_ 3840

typedef __attribute__((ext_vector_type(8))) short bf16x8;
typedef __attribute__((ext_vector_type(4))) float f32x4;
typedef __attribute__((ext_vector_type(8))) unsigned short us8;
typedef __attribute__((ext_vector_type(4))) unsigned short us4;

__device__ __forceinline__ unsigned short f2b(float f) {
  unsigned int u = __builtin_bit_cast(unsigned int, f);
  u += 0x7fffu + ((u >> 16) & 1u);
  return (unsigned short)(u >> 16);
}

__device__ __forceinline__ void gload_lds16(const void* g, void* l) {
  __builtin_amdgcn_global_load_lds(
      (const __attribute__((address_space(1))) unsigned int*)g,
      (__attribute__((address_space(3))) unsigned int*)l, 16, 0, 0);
}

#define WAITVM(N) asm volatile("s_waitcnt vmcnt(" #N ")" ::: "memory")

// ---------- transpose + f32->bf16: out[C][R] = bf16(in[R][C]) ----------
__global__ __launch_bounds__(256) void transp_bf16_kernel(
    const float* __restrict__ in, unsigned short* __restrict__ out, int R, int C) {
  __shared__ float tile[32][33];
  int c0 = blockIdx.x * 32, r0 = blockIdx.y * 32;
  int tx = threadIdx.x & 31, ty = threadIdx.x >> 5;
#pragma unroll
  for (int i = 0; i < 32; i += 8)
    tile[ty + i][tx] = in[(size_t)(r0 + ty + i) * C + c0 + tx];
  __syncthreads();
#pragma unroll
  for (int i = 0; i < 32; i += 8)
    out[(size_t)(c0 + ty + i) * R + r0 + tx] = f2b(tile[tx][ty + i]);
}

// ---------- layernorm f32 -> bf16 ----------
__global__ __launch_bounds__(256) void ln_kernel(
    const float* __restrict__ in, const float* __restrict__ g,
    const float* __restrict__ b, unsigned short* __restrict__ out) {
  int row = blockIdx.x, tid = threadIdx.x;
  int l = tid & 63, w = tid >> 6;
  const float* x = in + (size_t)row * DIM_;
  float v[5], s = 0.f, s2 = 0.f;
#pragma unroll
  for (int i = 0; i < 5; ++i) {
    v[i] = x[tid + i * 256];
    s += v[i];
    s2 += v[i] * v[i];
  }
#pragma unroll
  for (int off = 1; off < 64; off <<= 1) {
    s += __shfl_xor(s, off);
    s2 += __shfl_xor(s2, off);
  }
  __shared__ float red[8];
  if (l == 0) { red[w * 2] = s; red[w * 2 + 1] = s2; }
  __syncthreads();
  s = red[0] + red[2] + red[4] + red[6];
  s2 = red[1] + red[3] + red[5] + red[7];
  float mu = s * (1.f / DIM_);
  float var = s2 * (1.f / DIM_) - mu * mu;
  float rs = rsqrtf(var + 1e-5f);
#pragma unroll
  for (int i = 0; i < 5; ++i) {
    int c = tid + i * 256;
    out[(size_t)row * DIM_ + c] = f2b((v[i] - mu) * rs * g[c] + b[c]);
  }
}

// ---------- 128x256 GEMM, BK=32, 8 waves, 3-buffer counted-vmcnt pipeline ----
// LDS/buf 24KB: A [128r][4c][16B] @0, B [256r][4c][16B] @8192. 3 bufs = 72KB,
// 2 blocks/CU. XOR swizzle on row bits [2:1] (bit 0 already splits the bank
// group): phys chunk = kc ^ ((row>>1)&3), applied rule-#21 (pre-swizzled
// global source + swizzled ds_read, linear gload dest).
// Pipeline (T4): STAGE(t+2) at top; vmcnt(3) at boundary -- tile t+2's loads
// stay in flight across the barrier; drains to 0 only at the last boundary.
enum { EPI_QKV = 0, EPI_GELU = 3, EPI_PART = 4 };

template <int EPI>
__device__ __forceinline__ void gemm_body(
    const unsigned short* __restrict__ A, int lda,
    const unsigned short* __restrict__ Bt, int ldb,
    const float* __restrict__ bias, const float* __restrict__ bias2,
    void* __restrict__ out0, void* __restrict__ out1, void* __restrict__ out2,
    int M, int N, int K, int nz) {
  __shared__ char lds[3][24576];
  const int tid = threadIdx.x;
  const int l = tid & 63, w = tid >> 6;
  const int r16 = l & 15, kg4 = l >> 4;
  // M-band XCD swizzle (ny multiple of 8)
  const int nx = gridDim.x;
  const int orig = blockIdx.y * nx + blockIdx.x;
  const int xcd = orig & 7, idx = orig >> 3;
  const int by = xcd * (gridDim.y >> 3) + idx / nx;
  const int bx = idx % nx;
  const int m0 = by * 128, n0 = bx * 256;
  const int wm = (w >> 2) * 64, wn = (w & 3) * 64;
  // split-K (uneven): z in [0,nz)
  const int z = blockIdx.z;
  const int ntK = K >> 5;
  const int base = ntK / nz, rem = ntK % nz;
  const int k0 = z * base + (z < rem ? z : rem);
  const int nt = base + (z < rem ? 1 : 0);
  // staging sources: thread covers row=tid>>2, phys chunk cp=tid&3 which
  // holds logical chunk kc = cp ^ ((row>>1)&3) = (tid&3) ^ ((tid>>3)&3)
  const int kc = (tid & 3) ^ ((tid >> 3) & 3);
  const unsigned short* aA = A + (size_t)(m0 + (tid >> 2)) * lda + kc * 8 + k0 * 32;
  const unsigned short* aB = Bt + (size_t)(n0 + (tid >> 2)) * ldb + kc * 8 + k0 * 32;
  const unsigned short* aB1 = aB + (size_t)128 * ldb;
  // swizzled fragment read offsets (row bits [2:1] = r16 bits [2:1])
  const int cswz = (kg4 ^ ((r16 >> 1) & 3)) << 4;
  int aoff[4], boff[4];
#pragma unroll
  for (int mi = 0; mi < 4; ++mi) aoff[mi] = (wm + mi * 16 + r16) * 64 + cswz;
#pragma unroll
  for (int ni = 0; ni < 4; ++ni) boff[ni] = 8192 + (wn + ni * 16 + r16) * 64 + cswz;

  f32x4 acc[4][4] = {};

#define STAGE(b, kt_)                                          \
  do {                                                         \
    const int kb = (kt_) * 32;                                 \
    char* dA = &lds[0][0] + (b) * 24576 + w * 1024;            \
    char* dB = dA + 8192;                                      \
    gload_lds16(aA + kb, dA);                                  \
    gload_lds16(aB + kb, dB);                                  \
    gload_lds16(aB1 + kb, dB + 8192);                          \
  } while (0)

  STAGE(0, 0);
  if (nt > 1) {
    STAGE(1, 1);
    WAITVM(3);  // buf0's 3 loads done; buf1's 3 stay in flight
  } else {
    WAITVM(0);
  }
  __builtin_amdgcn_s_barrier();

  int cur = 0;
#pragma unroll 1
  for (int t = 0; t < nt; ++t) {
    if (t + 2 < nt) {
      int nxt = cur + 2; if (nxt >= 3) nxt -= 3;
      STAGE(nxt, t + 2);  // buf (t+2)%3 last read in iter t-1 (pre-barrier)
    }
    const char* sl = &lds[0][0] + cur * 24576;
    bf16x8 af[4], bfv[4];
#pragma unroll
    for (int mi = 0; mi < 4; ++mi) af[mi] = *(const bf16x8*)(sl + aoff[mi]);
#pragma unroll
    for (int ni = 0; ni < 4; ++ni) bfv[ni] = *(const bf16x8*)(sl + boff[ni]);
    __builtin_amdgcn_s_setprio(1);
#pragma unroll
    for (int mi = 0; mi < 4; ++mi)
#pragma unroll
      for (int ni = 0; ni < 4; ++ni)
        acc[mi][ni] = __builtin_amdgcn_mfma_f32_16x16x32_bf16(af[mi], bfv[ni], acc[mi][ni], 0, 0, 0);
    __builtin_amdgcn_s_setprio(0);
    if (t + 2 < nt) WAITVM(3);       // retire t+1's loads; t+2's stay in flight
    else if (t + 1 < nt) WAITVM(0);  // final boundary only
    if (t + 1 < nt) __builtin_amdgcn_s_barrier();
    ++cur; if (cur == 3) cur = 0;
  }
#undef STAGE

  const int rg = kg4 * 4;
#pragma unroll
  for (int mi = 0; mi < 4; ++mi) {
#pragma unroll
    for (int ni = 0; ni < 4; ++ni) {
      int row = m0 + wm + mi * 16 + rg;
      int col = n0 + wn + ni * 16 + r16;
      f32x4 v = acc[mi][ni];
      if constexpr (EPI == EPI_QKV) {
        if (col < DIM_) {  // Q (+bq)
          unsigned short* O = (unsigned short*)out0;
          float bb = bias[col];
#pragma unroll
          for (int j = 0; j < 4; ++j) O[(size_t)(row + j) * DIM_ + col] = f2b(v[j] + bb);
        } else if (col < 2 * DIM_) {  // K (no bias)
          unsigned short* O = (unsigned short*)out1;
          int cc = col - DIM_;
#pragma unroll
          for (int j = 0; j < 4; ++j) O[(size_t)(row + j) * DIM_ + cc] = f2b(v[j]);
        } else {  // V (+bv), transposed store -> Vt[d][s]
          unsigned short* O = (unsigned short*)out2;
          int cc = col - 2 * DIM_;
          float bb = bias2[cc];
          us4 pk;
#pragma unroll
          for (int j = 0; j < 4; ++j) pk[j] = f2b(v[j] + bb);
          *(us4*)(O + (size_t)cc * SEQ_ + row) = pk;
        }
      } else if constexpr (EPI == EPI_GELU) {
        unsigned short* O = (unsigned short*)out0;
        float bb = bias[col];
#pragma unroll
        for (int j = 0; j < 4; ++j) {
          float t = v[j] + bb;
          t = 0.5f * t * (1.f + erff(t * 0.70710678118f));
          O[(size_t)(row + j) * N + col] = f2b(t);
        }
      } else {  // EPI_PART: raw f32 partial per K-split
        float* O = (float*)out0 + (size_t)blockIdx.z * M * N;
#pragma unroll
        for (int j = 0; j < 4; ++j) O[(size_t)(row + j) * N + col] = v[j];
      }
    }
  }
}

// distinct names for rocprof attribution
__global__ __launch_bounds__(512, 4) void qkv_gemm(
    const unsigned short* A, const unsigned short* Bt, const float* bq,
    const float* bv, void* q, void* k, void* v) {
  gemm_body<EPI_QKV>(A, DIM_, Bt, DIM_, bq, bv, q, k, v, SEQ_, QKVN_, DIM_, 1);
}
__global__ __launch_bounds__(512, 4) void wo_gemm(
    const unsigned short* A, const unsigned short* Bt, void* part) {
  gemm_body<EPI_PART>(A, DIM_, Bt, DIM_, nullptr, nullptr, part, nullptr, nullptr,
                      SEQ_, DIM_, DIM_, 3);
}
__global__ __launch_bounds__(512, 4) void ffn1_gemm(
    const unsigned short* A, const unsigned short* Bt, const float* bf1, void* g) {
  gemm_body<EPI_GELU>(A, DIM_, Bt, DIM_, bf1, nullptr, g, nullptr, nullptr,
                      SEQ_, FFN_, DIM_, 1);
}
__global__ __launch_bounds__(512, 4) void ffn2_gemm(
    const unsigned short* A, const unsigned short* Bt, void* part) {
  gemm_body<EPI_PART>(A, FFN_, Bt, FFN_, nullptr, nullptr, part, nullptr, nullptr,
                      SEQ_, DIM_, FFN_, 3);
}

// ---------- split-K reduce (3-way): out = p0+p1+p2 + bias + res ----------
__global__ __launch_bounds__(256) void reduce3_kernel(
    const float* __restrict__ part, const float* __restrict__ bias,
    const float* __restrict__ res, float* __restrict__ out) {
  const size_t MN = (size_t)SEQ_ * DIM_;
  for (size_t i = blockIdx.x * 256 + threadIdx.x; i * 4 < MN; i += (size_t)gridDim.x * 256) {
    size_t e = i * 4;
    f32x4 a = *(const f32x4*)(part + e);
    f32x4 b = *(const f32x4*)(part + MN + e);
    f32x4 c = *(const f32x4*)(part + 2 * MN + e);
    f32x4 r = *(const f32x4*)(res + e);
    f32x4 bb = *(const f32x4*)(bias + (int)(e % DIM_));
    f32x4 o = a + b + c + r + bb;
    *(f32x4*)(out + e) = o;
  }
}

// ---------- attention: per (head, seg, 64-row q chunk) ----------
__global__ __launch_bounds__(256) void attn_kernel(
    const unsigned short* __restrict__ Q, const unsigned short* __restrict__ Kb,
    const unsigned short* __restrict__ Vt, unsigned short* __restrict__ O) {
  __shared__ float S[64][512];
  int tid = threadIdx.x;
  int l = tid & 63, w = tid >> 6;
  int orig = blockIdx.x;
  int b = (orig & 7) * (gridDim.x >> 3) + (orig >> 3);
  int qc = b & 7, seg = (b >> 3) & 7, hh = b >> 6;
  int r16 = l & 15, kg = l >> 4, rg = (l >> 4) * 4;
  int qrow0 = seg * SEG_ + qc * 64 + w * 16;
  bf16x8 aq[2];
#pragma unroll
  for (int ks = 0; ks < 2; ++ks)
    aq[ks] = *(const bf16x8*)(Q + (size_t)(qrow0 + r16) * DIM_ + hh * HDIM_ + ks * 32 + kg * 8);
#pragma unroll 4
  for (int kc = 0; kc < 32; ++kc) {
    f32x4 acc = {};
#pragma unroll
    for (int ks = 0; ks < 2; ++ks) {
      bf16x8 bk = *(const bf16x8*)(Kb + (size_t)(seg * SEG_ + kc * 16 + r16) * DIM_ +
                                   hh * HDIM_ + ks * 32 + kg * 8);
      acc = __builtin_amdgcn_mfma_f32_16x16x32_bf16(aq[ks], bk, acc, 0, 0, 0);
    }
#pragma unroll
    for (int j = 0; j < 4; ++j)
      S[w * 16 + rg + j][kc * 16 + r16] = acc[j] * 0.125f;
  }
#pragma unroll 2
  for (int r = 0; r < 16; ++r) {
    float* Sr = &S[w * 16 + r][0];
    f32x4 v0 = *(const f32x4*)(Sr + l * 8);
    f32x4 v1 = *(const f32x4*)(Sr + l * 8 + 4);
    float m = fmaxf(fmaxf(fmaxf(v0[0], v0[1]), fmaxf(v0[2], v0[3])),
                    fmaxf(fmaxf(v1[0], v1[1]), fmaxf(v1[2], v1[3])));
#pragma unroll
    for (int off = 1; off < 64; off <<= 1) m = fmaxf(m, __shfl_xor(m, off));
    float ev[8];
    ev[0] = v0[0]; ev[1] = v0[1]; ev[2] = v0[2]; ev[3] = v0[3];
    ev[4] = v1[0]; ev[5] = v1[1]; ev[6] = v1[2]; ev[7] = v1[3];
    float sum = 0.f;
#pragma unroll
    for (int j = 0; j < 8; ++j) { ev[j] = __expf(ev[j] - m); sum += ev[j]; }
#pragma unroll
    for (int off = 1; off < 64; off <<= 1) sum += __shfl_xor(sum, off);
    float inv = 1.f / sum;
    us8 pk;
#pragma unroll
    for (int j = 0; j < 8; ++j) pk[j] = f2b(ev[j] * inv);
    *(us8*)((unsigned short*)Sr + ((l ^ (r & 7)) * 8)) = pk;
  }
  f32x4 oacc[4] = {};
  const unsigned short* Pr = (const unsigned short*)&S[w * 16 + r16][0];
  int rowx = r16 & 7;
#pragma unroll 2
  for (int ks = 0; ks < 16; ++ks) {
    int chunk = (ks * 4 + kg) ^ rowx;
    bf16x8 pa = *(const bf16x8*)(Pr + chunk * 8);
#pragma unroll
    for (int df = 0; df < 4; ++df) {
      bf16x8 bv = *(const bf16x8*)(Vt + (size_t)(hh * HDIM_ + df * 16 + r16) * SEQ_ +
                                   seg * SEG_ + ks * 32 + kg * 8);
      oacc[df] = __builtin_amdgcn_mfma_f32_16x16x32_bf16(pa, bv, oacc[df], 0, 0, 0);
    }
  }
#pragma unroll
  for (int df = 0; df < 4; ++df)
#pragma unroll
    for (int j = 0; j < 4; ++j)
      O[(size_t)(qrow0 + rg + j) * DIM_ + hh * HDIM_ + df * 16 + r16] = f2b(oacc[df][j]);
}

extern "C" void kernel_launch(void* const* d_in, const int* in_sizes, int n_in,
                              void* d_out, int out_size, void* d_ws, size_t ws_size,
                              hipStream_t stream) {
  (void)in_sizes; (void)n_in; (void)out_size; (void)ws_size;
  const float* hidden = (const float*)d_in[0];
  const float* Wq = (const float*)d_in[2];
  const float* bq = (const float*)d_in[3];
  const float* Wk = (const float*)d_in[4];
  const float* Wv = (const float*)d_in[5];
  const float* bv = (const float*)d_in[6];
  const float* Wo = (const float*)d_in[7];
  const float* bo = (const float*)d_in[8];
  const float* g1 = (const float*)d_in[9];
  const float* b1 = (const float*)d_in[10];
  const float* Wf1 = (const float*)d_in[11];
  const float* bf1 = (const float*)d_in[12];
  const float* Wf2 = (const float*)d_in[13];
  const float* bf2 = (const float*)d_in[14];
  const float* g2 = (const float*)d_in[15];
  const float* b2 = (const float*)d_in[16];

  char* p = (char*)d_ws;
  auto alloc = [&](size_t bytes) {
    char* r = p;
    p += (bytes + 255) & ~(size_t)255;
    return r;
  };
  unsigned short* xln   = (unsigned short*)alloc((size_t)SEQ_ * DIM_ * 2);
  unsigned short* Wqkvt = (unsigned short*)alloc((size_t)DIM_ * QKVN_ * 2);
  unsigned short* Wot   = (unsigned short*)alloc((size_t)DIM_ * DIM_ * 2);
  unsigned short* Wf1t  = (unsigned short*)alloc((size_t)DIM_ * FFN_ * 2);
  unsigned short* Wf2t  = (unsigned short*)alloc((size_t)DIM_ * FFN_ * 2);
  unsigned short* Qb    = (unsigned short*)alloc((size_t)SEQ_ * DIM_ * 2);
  unsigned short* Kbf   = (unsigned short*)alloc((size_t)SEQ_ * DIM_ * 2);
  unsigned short* Vtb   = (unsigned short*)alloc((size_t)SEQ_ * DIM_ * 2);
  unsigned short* attnb = (unsigned short*)alloc((size_t)SEQ_ * DIM_ * 2);
  float*          hbuf  = (float*)alloc((size_t)SEQ_ * DIM_ * 4);
  unsigned short* ybuf  = (unsigned short*)alloc((size_t)SEQ_ * DIM_ * 2);
  unsigned short* gbuf  = (unsigned short*)alloc((size_t)SEQ_ * FFN_ * 2);
  float*          part3 = (float*)alloc((size_t)3 * SEQ_ * DIM_ * 4);

  transp_bf16_kernel<<<dim3(DIM_ / 32, DIM_ / 32), 256, 0, stream>>>(Wq, Wqkvt, DIM_, DIM_);
  transp_bf16_kernel<<<dim3(DIM_ / 32, DIM_ / 32), 256, 0, stream>>>(Wk, Wqkvt + (size_t)DIM_ * DIM_, DIM_, DIM_);
  transp_bf16_kernel<<<dim3(DIM_ / 32, DIM_ / 32), 256, 0, stream>>>(Wv, Wqkvt + (size_t)2 * DIM_ * DIM_, DIM_, DIM_);
  transp_bf16_kernel<<<dim3(DIM_ / 32, DIM_ / 32), 256, 0, stream>>>(Wo, Wot, DIM_, DIM_);
  transp_bf16_kernel<<<dim3(FFN_ / 32, DIM_ / 32), 256, 0, stream>>>(Wf1, Wf1t, DIM_, FFN_);
  transp_bf16_kernel<<<dim3(DIM_ / 32, FFN_ / 32), 256, 0, stream>>>(Wf2, Wf2t, FFN_, DIM_);
  ln_kernel<<<SEQ_, 256, 0, stream>>>(hidden, g1, b1, xln);
  // QKV: 15x32 = 480 blocks, single round at 2 blocks/CU
  qkv_gemm<<<dim3(QKVN_ / 256, SEQ_ / 128), 512, 0, stream>>>(
      xln, Wqkvt, bq, bv, Qb, Kbf, Vtb);
  attn_kernel<<<NHEAD_ * 8 * 8, 256, 0, stream>>>(Qb, Kbf, Vtb, attnb);
  // Wo split-K=3: 5x32x3 = 480 blocks; reduce adds bias+residual
  wo_gemm<<<dim3(DIM_ / 256, SEQ_ / 128, 3), 512, 0, stream>>>(attnb, Wot, part3);
  reduce3_kernel<<<2048, 256, 0, stream>>>(part3, bo, hidden, hbuf);
  ln_kernel<<<SEQ_, 256, 0, stream>>>(hbuf, g2, b2, ybuf);
  // FFN1 + GELU: 20x32 = 640 blocks
  ffn1_gemm<<<dim3(FFN_ / 256, SEQ_ / 128), 512, 0, stream>>>(ybuf, Wf1t, bf1, gbuf);
  // FFN2 split-K=3: 5x32x3 = 480 blocks; reduce -> d_out
  ffn2_gemm<<<dim3(DIM_ / 256, SEQ_ / 128, 3), 512, 0, stream>>>(gbuf, Wf2t, part3);
  reduce3_kernel<<<2048, 256, 0, stream>>>(part3, bf2, hbuf, (float*)d_out);
}